// Round 1
// baseline (1570.492 us; speedup 1.0000x reference)
//
#include <hip/hip_runtime.h>
#include <math.h>

#define HH 1024
#define EE 512
#define VV 50257
#define BB 64
#define SS 1024
#define D2H 2048      // 2*H
#define KX 3584       // 2H + E + H
#define G4 4096       // 4H
#define PCH 16        // attention S-chunks per batch row
#define CH (SS/PCH)   // 64 s-rows per block

// ---------------- K1: hb[b] = dot(hidden[b], We[2048:3072]) + be ----------------
__global__ void hb_kernel(const float* __restrict__ hidden, const float* __restrict__ We,
                          const float* __restrict__ be, float* __restrict__ hb) {
    int b = blockIdx.x;
    int t = threadIdx.x;                  // 256 threads, 4 floats each = 1024
    float4 hv = *(const float4*)(hidden + (size_t)b*HH + t*4);
    float4 wv = *(const float4*)(We + D2H + t*4);
    float pd = hv.x*wv.x + hv.y*wv.y + hv.z*wv.z + hv.w*wv.w;
    #pragma unroll
    for (int off = 32; off; off >>= 1) pd += __shfl_down(pd, off);
    __shared__ float red[4];
    int wave = t >> 6, lane = t & 63;
    if (lane == 0) red[wave] = pd;
    __syncthreads();
    if (t == 0) hb[b] = red[0] + red[1] + red[2] + red[3] + be[0];
}

// ---------------- K2: flash attention over S (one pass over encoder_states) -----
__global__ __launch_bounds__(256) void attn_flash(
        const float* __restrict__ enc, const float* __restrict__ We,
        const float* __restrict__ hb,
        float* __restrict__ m_arr, float* __restrict__ l_arr, float* __restrict__ o_arr) {
    int chunk = blockIdx.x;   // 0..PCH-1
    int b     = blockIdx.y;   // 0..BB-1
    int t     = threadIdx.x;  // 256 threads; thread owns dims [t*8, t*8+8)
    const int d0 = t * 8;
    float4 w0 = *(const float4*)(We + d0);
    float4 w1 = *(const float4*)(We + d0 + 4);
    float hbb = hb[b];
    const float* base = enc + ((size_t)b*SS + (size_t)chunk*CH) * D2H + d0;

    float m = -INFINITY, l = 0.f;
    float4 o0 = {0,0,0,0}, o1 = {0,0,0,0};
    float4 c0 = *(const float4*)(base);
    float4 c1 = *(const float4*)(base + 4);
    __shared__ float red[8];
    int wave = t >> 6, lane = t & 63;

    for (int s = 0; s < CH; ++s) {
        float4 n0 = c0, n1 = c1;
        if (s + 1 < CH) {
            n0 = *(const float4*)(base + (size_t)(s+1)*D2H);
            n1 = *(const float4*)(base + (size_t)(s+1)*D2H + 4);
        }
        float pd = c0.x*w0.x + c0.y*w0.y + c0.z*w0.z + c0.w*w0.w
                 + c1.x*w1.x + c1.y*w1.y + c1.z*w1.z + c1.w*w1.w;
        #pragma unroll
        for (int off = 32; off; off >>= 1) pd += __shfl_down(pd, off);
        int slot = (s & 1) * 4;
        if (lane == 0) red[slot + wave] = pd;
        __syncthreads();
        float e = red[slot] + red[slot+1] + red[slot+2] + red[slot+3] + hbb;
        e = fmaxf(e, 0.f);                       // ReLU before softmax
        float nm    = fmaxf(m, e);
        float alpha = __expf(m - nm);
        float w     = __expf(e - nm);
        l = l * alpha + w;
        o0.x = o0.x*alpha + w*c0.x;  o0.y = o0.y*alpha + w*c0.y;
        o0.z = o0.z*alpha + w*c0.z;  o0.w = o0.w*alpha + w*c0.w;
        o1.x = o1.x*alpha + w*c1.x;  o1.y = o1.y*alpha + w*c1.y;
        o1.z = o1.z*alpha + w*c1.z;  o1.w = o1.w*alpha + w*c1.w;
        m = nm;
        c0 = n0; c1 = n1;
    }
    if (t == 0) { m_arr[b*PCH + chunk] = m; l_arr[b*PCH + chunk] = l; }
    float* op = o_arr + (size_t)(b*PCH + chunk) * D2H + d0;
    *(float4*)op       = o0;
    *(float4*)(op + 4) = o1;
}

// ------------- K3: combine partials -> c_i, build x_full = [c_i | emb | hidden] --
__global__ void attn_combine(const float* __restrict__ m_arr, const float* __restrict__ l_arr,
                             const float* __restrict__ o_arr,
                             const float* __restrict__ emb, const int* __restrict__ x_tok,
                             const float* __restrict__ hidden,
                             float* __restrict__ x_full) {
    int b = blockIdx.x;
    int t = threadIdx.x;  // 256
    float mv[PCH], f[PCH];
    float M = -INFINITY;
    #pragma unroll
    for (int p = 0; p < PCH; ++p) { mv[p] = m_arr[b*PCH + p]; M = fmaxf(M, mv[p]); }
    float L = 0.f;
    #pragma unroll
    for (int p = 0; p < PCH; ++p) { f[p] = __expf(mv[p] - M); L += l_arr[b*PCH + p] * f[p]; }
    float inv = 1.f / L;

    int d0 = t * 8;
    float4 a0 = {0,0,0,0}, a1 = {0,0,0,0};
    #pragma unroll
    for (int p = 0; p < PCH; ++p) {
        const float* op = o_arr + (size_t)(b*PCH + p) * D2H + d0;
        float4 v0 = *(const float4*)op;
        float4 v1 = *(const float4*)(op + 4);
        a0.x += v0.x*f[p]; a0.y += v0.y*f[p]; a0.z += v0.z*f[p]; a0.w += v0.w*f[p];
        a1.x += v1.x*f[p]; a1.y += v1.y*f[p]; a1.z += v1.z*f[p]; a1.w += v1.w*f[p];
    }
    a0.x *= inv; a0.y *= inv; a0.z *= inv; a0.w *= inv;
    a1.x *= inv; a1.y *= inv; a1.z *= inv; a1.w *= inv;
    float* xf = x_full + (size_t)b*KX + d0;
    *(float4*)xf       = a0;
    *(float4*)(xf + 4) = a1;

    // emb slice [2048:2560)
    int tok = x_tok[b];
    if (t < 128) {
        float4 v = *(const float4*)(emb + (size_t)tok*EE + t*4);
        *(float4*)(x_full + (size_t)b*KX + D2H + t*4) = v;
    }
    // hidden slice [2560:3584)
    float4 hv = *(const float4*)(hidden + (size_t)b*HH + t*4);
    *(float4*)(x_full + (size_t)b*KX + D2H + EE + t*4) = hv;
}

// ---------------- K4: gates = x_full @ [W_ih|W_hh]^T + b_ih + b_hh --------------
__global__ __launch_bounds__(256) void gates_gemm(
        const float* __restrict__ x_full,
        const float* __restrict__ W_ih, const float* __restrict__ W_hh,
        const float* __restrict__ b_ih, const float* __restrict__ b_hh,
        float* __restrict__ gates) {
    __shared__ float Xs[32][68];
    __shared__ float Ws[32][68];
    int j0 = blockIdx.x * 64;
    int t  = threadIdx.x;
    int tj = t & 15, tb = t >> 4;
    int kl = t & 31, rl = t >> 5;  // kl: k within tile, rl: row group 0..7
    float acc[4][4] = {};
    for (int kt = 0; kt < 112; ++kt) {
        #pragma unroll
        for (int p = 0; p < 8; ++p) {
            int row = rl + p*8;                       // 0..63
            Xs[kl][row] = x_full[(size_t)row*KX + kt*32 + kl];
            int j = j0 + row;
            float wv;
            if (kt < 80) wv = W_ih[(size_t)j*2560 + (size_t)kt*32 + kl];
            else         wv = W_hh[(size_t)j*1024 + (size_t)(kt-80)*32 + kl];
            Ws[kl][row] = wv;
        }
        __syncthreads();
        #pragma unroll
        for (int k = 0; k < 32; ++k) {
            float4 xv = *(const float4*)&Xs[k][tb*4];
            float4 wv = *(const float4*)&Ws[k][tj*4];
            float xa[4] = {xv.x, xv.y, xv.z, xv.w};
            float wa[4] = {wv.x, wv.y, wv.z, wv.w};
            #pragma unroll
            for (int bi = 0; bi < 4; ++bi)
                #pragma unroll
                for (int ji = 0; ji < 4; ++ji)
                    acc[bi][ji] = fmaf(xa[bi], wa[ji], acc[bi][ji]);
        }
        __syncthreads();
    }
    #pragma unroll
    for (int bi = 0; bi < 4; ++bi)
        #pragma unroll
        for (int ji = 0; ji < 4; ++ji) {
            int bb = tb*4 + bi;
            int j  = j0 + tj*4 + ji;
            gates[(size_t)bb*G4 + j] = acc[bi][ji] + b_ih[j] + b_hh[j];
        }
}

// ---------------- K5: LSTM elementwise ------------------------------------------
__global__ void lstm_elem(const float* __restrict__ gates, const float* __restrict__ cell,
                          float* __restrict__ h_out, float* __restrict__ c_out) {
    int idx = blockIdx.x * 256 + threadIdx.x;   // 0..65535
    int b = idx >> 10, hh = idx & 1023;
    const float* g = gates + (size_t)b * G4;
    float gi = g[hh], gf = g[hh+1024], gg = g[hh+2048], go = g[hh+3072];
    float si = 1.f / (1.f + __expf(-gi));
    float sf = 1.f / (1.f + __expf(-gf));
    float so = 1.f / (1.f + __expf(-go));
    float c  = sf * cell[idx] + si * tanhf(gg);
    float hn = so * tanhf(c);
    c_out[idx] = c;
    h_out[idx] = hn;
}

// ---------------- K6: predictions = h_next @ Wf^T + bf --------------------------
__global__ __launch_bounds__(256) void proj_gemm(
        const float* __restrict__ h, const float* __restrict__ Wf,
        const float* __restrict__ bf, float* __restrict__ pred) {
    __shared__ float Hs[32][68];
    __shared__ float Ws[32][68];
    int v0 = blockIdx.x * 64;
    int t  = threadIdx.x;
    int tj = t & 15, tb = t >> 4;
    int kl = t & 31, rl = t >> 5;
    float acc[4][4] = {};
    for (int kt = 0; kt < 32; ++kt) {
        #pragma unroll
        for (int p = 0; p < 8; ++p) {
            int row = rl + p*8;
            Hs[kl][row] = h[(size_t)row*HH + kt*32 + kl];
            int v = v0 + row;
            Ws[kl][row] = (v < VV) ? Wf[(size_t)v*HH + (size_t)kt*32 + kl] : 0.f;
        }
        __syncthreads();
        #pragma unroll
        for (int k = 0; k < 32; ++k) {
            float4 xv = *(const float4*)&Hs[k][tb*4];
            float4 wv = *(const float4*)&Ws[k][tj*4];
            float xa[4] = {xv.x, xv.y, xv.z, xv.w};
            float wa[4] = {wv.x, wv.y, wv.z, wv.w};
            #pragma unroll
            for (int bi = 0; bi < 4; ++bi)
                #pragma unroll
                for (int ji = 0; ji < 4; ++ji)
                    acc[bi][ji] = fmaf(xa[bi], wa[ji], acc[bi][ji]);
        }
        __syncthreads();
    }
    #pragma unroll
    for (int bi = 0; bi < 4; ++bi)
        #pragma unroll
        for (int ji = 0; ji < 4; ++ji) {
            int bb = tb*4 + bi;
            int v  = v0 + tj*4 + ji;
            if (v < VV) pred[(size_t)bb*VV + v] = acc[bi][ji] + bf[v];
        }
}

extern "C" void kernel_launch(void* const* d_in, const int* in_sizes, int n_in,
                              void* d_out, int out_size, void* d_ws, size_t ws_size,
                              hipStream_t stream) {
    const float* enc    = (const float*)d_in[0];
    const int*   x_tok  = (const int*)  d_in[1];
    const float* hidden = (const float*)d_in[2];
    const float* cell   = (const float*)d_in[3];
    const float* emb    = (const float*)d_in[4];
    const float* We     = (const float*)d_in[5];
    const float* be     = (const float*)d_in[6];
    const float* W_ih   = (const float*)d_in[7];
    const float* W_hh   = (const float*)d_in[8];
    const float* b_ih   = (const float*)d_in[9];
    const float* b_hh   = (const float*)d_in[10];
    const float* Wf     = (const float*)d_in[11];
    const float* bf     = (const float*)d_in[12];

    float* out   = (float*)d_out;
    float* pred  = out;                               // B*V
    float* h_out = out + (size_t)BB * VV;             // B*H
    float* c_out = h_out + (size_t)BB * HH;           // B*H

    float* ws     = (float*)d_ws;
    float* hb     = ws;                               // 64
    float* m_arr  = ws + 64;                          // B*PCH = 1024
    float* l_arr  = m_arr + BB*PCH;                   // 1024
    float* o_arr  = l_arr + BB*PCH;                   // B*PCH*2048 = 2,097,152
    float* x_full = o_arr + (size_t)BB*PCH*D2H;       // B*KX = 229,376
    float* gates  = x_full + (size_t)BB*KX;           // B*4H = 262,144
    // total ~10.4 MB of d_ws

    hb_kernel   <<<BB, 256, 0, stream>>>(hidden, We, be, hb);
    attn_flash  <<<dim3(PCH, BB), 256, 0, stream>>>(enc, We, hb, m_arr, l_arr, o_arr);
    attn_combine<<<BB, 256, 0, stream>>>(m_arr, l_arr, o_arr, emb, x_tok, hidden, x_full);
    gates_gemm  <<<G4/64, 256, 0, stream>>>(x_full, W_ih, W_hh, b_ih, b_hh, gates);
    lstm_elem   <<<(BB*HH)/256, 256, 0, stream>>>(gates, cell, h_out, c_out);
    proj_gemm   <<<(VV + 63)/64, 256, 0, stream>>>(h_out, Wf, bf, pred);
}